// Round 1
// baseline (1036.213 us; speedup 1.0000x reference)
//
#include <hip/hip_runtime.h>

// ---------------------------------------------------------------------------
// RelPositionMultiHeadedAttention (Conformer / Transformer-XL rel-shift)
// B=4, T=2048, C=512, H=8, D=64
//
// Pipeline:
//   1) proj_kernel  : fp32 tiled GEMM, z in {Q,K,V,P}. Writes bf16 [B,H,T,D]
//                     arrays to ws: QU=bf16(q+u), QV=bf16(q+v), K16, V16, P16.
//   2) attn_kernel  : flash-style online-softmax attention, bf16 MFMA
//                     (16x16x32). Pos scores via banded matmul + LDS gather:
//                       j<=i   : (q_i+v)·p[T-1+j-i]
//                       j==i+1 : 0
//                       j>=i+2 : (q_{i+1}+v)·p[j-i-2]
//                     Writes fp32 ctx [B,T,C] to ws.
//   3) gemm_out     : fp32 tiled GEMM ctx@Wo + bo -> d_out (fp32 keeps the
//                     error-critical final projection exact-ish).
//
// ws usage: 5 * 8MB bf16 + 16MB fp32 = 56 MB.
// ---------------------------------------------------------------------------

#define Bb 4
#define Tt 2048
#define Cc 512
#define Hh 8
#define Dd 64

typedef __bf16 bf16_t;
typedef __bf16 bf16x8 __attribute__((ext_vector_type(8)));
typedef float  f32x4  __attribute__((ext_vector_type(4)));

// ---------------------------------------------------------------------------
// Kernel 1: fused QKVP projections, fp32. BM=128, BN=64, BK=16, 256 thr,
// 8x4 microtile. z selects which projection.
// ---------------------------------------------------------------------------
__global__ __launch_bounds__(256)
void proj_kernel(const float* __restrict__ Xq, const float* __restrict__ Xk,
                 const float* __restrict__ Xv, const float* __restrict__ Xp,
                 const float* __restrict__ Wq, const float* __restrict__ Wk,
                 const float* __restrict__ Wv, const float* __restrict__ Wp,
                 const float* __restrict__ bq, const float* __restrict__ bk,
                 const float* __restrict__ bv,
                 const float* __restrict__ bias_u, const float* __restrict__ bias_v,
                 bf16_t* __restrict__ QU, bf16_t* __restrict__ QV,
                 bf16_t* __restrict__ K16, bf16_t* __restrict__ V16,
                 bf16_t* __restrict__ P16)
{
    const int z = blockIdx.z;
    const float* X    = (z == 0) ? Xq : (z == 1) ? Xk : (z == 2) ? Xv : Xp;
    const float* W    = (z == 0) ? Wq : (z == 1) ? Wk : (z == 2) ? Wv : Wp;
    const float* bias = (z == 0) ? bq : (z == 1) ? bk : (z == 2) ? bv : nullptr;

    const int r0 = blockIdx.y * 128;
    const int c0 = blockIdx.x * 64;
    const int tid = threadIdx.x;
    const int ti = tid >> 4;   // 0..15 -> 8 rows each
    const int tj = tid & 15;   // 0..15 -> 4 cols each

    __shared__ __align__(16) float As[16][136]; // [kk][i], stride 136 keeps 16B align, breaks bank stride
    __shared__ __align__(16) float Bs[16][68];  // [kk][j]

    float acc[8][4];
#pragma unroll
    for (int r = 0; r < 8; r++)
#pragma unroll
        for (int c = 0; c < 4; c++) acc[r][c] = 0.f;

    for (int k0 = 0; k0 < 512; k0 += 16) {
        {
            int kk = tid & 15, ibase = tid >> 4;
#pragma unroll
            for (int p = 0; p < 8; p++) {
                int i = ibase + p * 16;
                As[kk][i] = X[(size_t)(r0 + i) * 512 + k0 + kk];
            }
            int j = tid & 63, kb = tid >> 6;
#pragma unroll
            for (int p = 0; p < 4; p++) {
                int kk2 = kb + p * 4;
                Bs[kk2][j] = W[(size_t)(k0 + kk2) * 512 + c0 + j];
            }
        }
        __syncthreads();
#pragma unroll
        for (int kk = 0; kk < 16; kk++) {
            f32x4 a0 = *(const f32x4*)&As[kk][ti * 8];
            f32x4 a1 = *(const f32x4*)&As[kk][ti * 8 + 4];
            f32x4 b0 = *(const f32x4*)&Bs[kk][tj * 4];
#pragma unroll
            for (int r = 0; r < 4; r++)
#pragma unroll
                for (int c = 0; c < 4; c++) {
                    acc[r][c]     = fmaf(a0[r], b0[c], acc[r][c]);
                    acc[r + 4][c] = fmaf(a1[r], b0[c], acc[r + 4][c]);
                }
        }
        __syncthreads();
    }

#pragma unroll
    for (int r = 0; r < 8; r++) {
        int row = r0 + ti * 8 + r;
        int b = row >> 11, t = row & 2047;
#pragma unroll
        for (int c = 0; c < 4; c++) {
            int col = c0 + tj * 4 + c;
            int h = col >> 6, d = col & 63;
            float y = acc[r][c] + (bias ? bias[col] : 0.f);
            size_t idx = (((size_t)(b * Hh + h)) * Tt + t) * Dd + d;
            if (z == 0) {
                QU[idx] = (bf16_t)(y + bias_u[col]);  // bias_u flat [H*D] == col
                QV[idx] = (bf16_t)(y + bias_v[col]);
            } else if (z == 1) {
                K16[idx] = (bf16_t)y;
            } else if (z == 2) {
                V16[idx] = (bf16_t)y;
            } else {
                P16[idx] = (bf16_t)y;
            }
        }
    }
}

// ---------------------------------------------------------------------------
// Kernel 2: attention. 64 query rows / block (4 waves x 16-row strips),
// j-tiles of 64, online softmax, bf16 MFMA 16x16x32.
// ---------------------------------------------------------------------------
__global__ __launch_bounds__(256, 1)
void attn_kernel(const bf16_t* __restrict__ QU, const bf16_t* __restrict__ QV,
                 const bf16_t* __restrict__ K16, const bf16_t* __restrict__ V16,
                 const bf16_t* __restrict__ P16, float* __restrict__ CTX)
{
    const int i0 = blockIdx.x * 64;
    const int bh = blockIdx.y;
    const int b = bh >> 3, h = bh & 7;
    const int tid = threadIdx.x;
    const int wave = tid >> 6;
    const int lane = tid & 63;
    const int quad = lane >> 4;
    const int l16 = lane & 15;

    const size_t hb = (size_t)bh * Tt * Dd;
    const bf16_t* qu_g = QU + hb;
    const bf16_t* qv_g = QV + hb;
    const bf16_t* k_g  = K16 + hb;
    const bf16_t* v_g  = V16 + hb;
    const bf16_t* p_g  = P16 + hb;

    __shared__ __align__(16) bf16_t qu_s[64][72];
    __shared__ __align__(16) bf16_t qv_s[65][72];   // row i0+64 needed for j>=i+2 wrap
    __shared__ __align__(16) bf16_t k_s[64][72];
    __shared__ __align__(16) bf16_t vT_s[64][72];   // [d][j]
    __shared__ __align__(16) bf16_t p_s[144][72];   // band rows (<=144 incl. 16-pad)
    __shared__ __align__(16) bf16_t w_s[64][72];    // softmax weights (bf16) for PV A-frag
    __shared__ __align__(16) float  ms_s[64][148];  // banded pos matmul output

    // stage qu (64 rows), qv (65 rows, clamped)
    for (int idx = tid; idx < 64 * 8; idx += 256) {
        int row = idx >> 3, seg = idx & 7;
        *(f32x4*)&qu_s[row][seg * 8] = *(const f32x4*)(qu_g + (size_t)(i0 + row) * Dd + seg * 8);
    }
    for (int idx = tid; idx < 65 * 8; idx += 256) {
        int row = idx >> 3, seg = idx & 7;
        int gr = i0 + row; if (gr > Tt - 1) gr = Tt - 1;  // clamped row is never gathered
        *(f32x4*)&qv_s[row][seg * 8] = *(const f32x4*)(qv_g + (size_t)gr * Dd + seg * 8);
    }
    __syncthreads();

    // A-operand fragments: lane holds A[m=l16][k=quad*8+e], k-chunks of 32
    bf16x8 aq[2], av1[2], av2[2];
#pragma unroll
    for (int kc = 0; kc < 2; kc++) {
        aq[kc]  = *(const bf16x8*)&qu_s[wave * 16 + l16][kc * 32 + quad * 8];
        av1[kc] = *(const bf16x8*)&qv_s[wave * 16 + l16][kc * 32 + quad * 8];
        av2[kc] = *(const bf16x8*)&qv_s[wave * 16 + l16 + 1][kc * 32 + quad * 8];
    }

    float mrow[4], lrow[4];
    f32x4 accO[4];
#pragma unroll
    for (int r = 0; r < 4; r++) { mrow[r] = -1e30f; lrow[r] = 0.f; }
#pragma unroll
    for (int dt = 0; dt < 4; dt++)
#pragma unroll
        for (int r = 0; r < 4; r++) accO[dt][r] = 0.f;

    for (int j0 = 0; j0 < Tt; j0 += 64) {
        // band parameters (d = ig - jg over the tile)
        int d_lo = i0 - (j0 + 63);
        int d_hi = i0 + 63 - j0;
        int w1 = 0, prow1 = 0;
        if (d_hi >= 0) {
            int b1 = d_lo > 0 ? d_lo : 0;
            w1 = d_hi - b1 + 1;
            prow1 = (Tt - 1) - d_hi;             // p rows [prow1, prow1+w1)
        }
        int dmax2 = d_hi < -2 ? d_hi : -2;
        int w2 = 0, e_lo = 0;
        if (d_lo <= dmax2) {
            e_lo = -dmax2 - 2;
            int e_hi = -d_lo - 2;
            w2 = e_hi - e_lo + 1;                // p rows [e_lo, e_lo+w2)
        }
        int w1pad = (w1 + 15) & ~15;
        int w2pad = (w2 + 15) & ~15;
        int nct1 = w1pad >> 4;
        int nct  = nct1 + (w2pad >> 4);

        // stage K tile
        for (int idx = tid; idx < 64 * 8; idx += 256) {
            int row = idx >> 3, seg = idx & 7;
            *(f32x4*)&k_s[row][seg * 8] = *(const f32x4*)(k_g + (size_t)(j0 + row) * Dd + seg * 8);
        }
        // stage V tile transposed
        for (int idx = tid; idx < 64 * 8; idx += 256) {
            int j = idx >> 3, seg = idx & 7;
            bf16x8 tmp = *(const bf16x8*)(v_g + (size_t)(j0 + j) * Dd + seg * 8);
#pragma unroll
            for (int e = 0; e < 8; e++) vT_s[seg * 8 + e][j] = tmp[e];
        }
        // stage p bands: [0,w1) <- p[prow1..], [w1pad, w1pad+w2) <- p[e_lo..]
        for (int idx = tid; idx < (w1 + w2) * 8; idx += 256) {
            int rr = idx >> 3, seg = idx & 7;
            int dstrow, srcrow;
            if (rr < w1) { dstrow = rr;                 srcrow = prow1 + rr; }
            else         { dstrow = w1pad + (rr - w1);  srcrow = e_lo + (rr - w1); }
            *(f32x4*)&p_s[dstrow][seg * 8] = *(const f32x4*)(p_g + (size_t)srcrow * Dd + seg * 8);
        }
        __syncthreads();

        // content scores: S[16x64] per wave
        f32x4 accS[4];
#pragma unroll
        for (int nt = 0; nt < 4; nt++) {
            f32x4 acc = {0.f, 0.f, 0.f, 0.f};
#pragma unroll
            for (int kc = 0; kc < 2; kc++) {
                bf16x8 bk8 = *(const bf16x8*)&k_s[nt * 16 + l16][kc * 32 + quad * 8];
                acc = __builtin_amdgcn_mfma_f32_16x16x32_bf16(aq[kc], bk8, acc, 0, 0, 0);
            }
            accS[nt] = acc;
        }

        // banded pos matmul -> ms_s (each wave writes+reads only its own strip)
        for (int ct = 0; ct < nct; ct++) {
            f32x4 acc = {0.f, 0.f, 0.f, 0.f};
            const bf16x8* A = (ct < nct1) ? av1 : av2;  // band2 uses q_{i+1}
#pragma unroll
            for (int kc = 0; kc < 2; kc++) {
                bf16x8 bp = *(const bf16x8*)&p_s[ct * 16 + l16][kc * 32 + quad * 8];
                acc = __builtin_amdgcn_mfma_f32_16x16x32_bf16(A[kc], bp, acc, 0, 0, 0);
            }
#pragma unroll
            for (int r = 0; r < 4; r++)
                ms_s[wave * 16 + quad * 4 + r][ct * 16 + l16] = acc[r];
        }
        __syncthreads();

        // gather pos + scale
        float sc[4][4];
#pragma unroll
        for (int nt = 0; nt < 4; nt++) {
            int jg = j0 + nt * 16 + l16;
#pragma unroll
            for (int r = 0; r < 4; r++) {
                int il = wave * 16 + quad * 4 + r;
                int ig = i0 + il;
                int dd = ig - jg;
                float pos;
                if (dd >= 0)       pos = ms_s[il][d_hi - dd];                  // (q_i+v)·p[T-1-dd]
                else if (dd == -1) pos = 0.f;                                  // shift zero column
                else               pos = ms_s[il][w1pad + (-dd - 2 - e_lo)];   // (q_{i+1}+v)·p[jg-ig-2]
                sc[nt][r] = (accS[nt][r] + pos) * 0.125f;
            }
        }

        // online softmax (register-resident; reduce across the 16 lanes of a quad)
#pragma unroll
        for (int r = 0; r < 4; r++) {
            float mx = fmaxf(fmaxf(sc[0][r], sc[1][r]), fmaxf(sc[2][r], sc[3][r]));
#pragma unroll
            for (int off = 1; off < 16; off <<= 1) mx = fmaxf(mx, __shfl_xor(mx, off, 64));
            float mnew = fmaxf(mrow[r], mx);
            float alpha = __expf(mrow[r] - mnew);
            mrow[r] = mnew;
            float rsum = 0.f;
#pragma unroll
            for (int nt = 0; nt < 4; nt++) {
                float w = __expf(sc[nt][r] - mnew);
                sc[nt][r] = w;
                rsum += w;
            }
#pragma unroll
            for (int off = 1; off < 16; off <<= 1) rsum += __shfl_xor(rsum, off, 64);
            lrow[r] = lrow[r] * alpha + rsum;
#pragma unroll
            for (int dt = 0; dt < 4; dt++) accO[dt][r] *= alpha;
            int il = wave * 16 + quad * 4 + r;
#pragma unroll
            for (int nt = 0; nt < 4; nt++)
                w_s[il][nt * 16 + l16] = (bf16_t)sc[nt][r];
        }
        __syncthreads();

        // O += W @ V   (A = weights [m=i][k=j], B = V^T [n=d][k=j])
#pragma unroll
        for (int kc = 0; kc < 2; kc++) {
            bf16x8 aw = *(const bf16x8*)&w_s[wave * 16 + l16][kc * 32 + quad * 8];
#pragma unroll
            for (int dt = 0; dt < 4; dt++) {
                bf16x8 bv8 = *(const bf16x8*)&vT_s[dt * 16 + l16][kc * 32 + quad * 8];
                accO[dt] = __builtin_amdgcn_mfma_f32_16x16x32_bf16(aw, bv8, accO[dt], 0, 0, 0);
            }
        }
        __syncthreads();  // protect k_s/vT_s/p_s/w_s before next stage
    }

    // epilogue: O / l -> ctx [B,T,C]
#pragma unroll
    for (int r = 0; r < 4; r++) {
        int il = wave * 16 + quad * 4 + r;
        int ig = i0 + il;
        float inv = 1.0f / lrow[r];
#pragma unroll
        for (int dt = 0; dt < 4; dt++) {
            CTX[((size_t)(b * Tt + ig)) * Cc + h * Dd + dt * 16 + l16] = accO[dt][r] * inv;
        }
    }
}

// ---------------------------------------------------------------------------
// Kernel 3: output projection, fp32 (precision-critical). Same tiling as proj.
// ---------------------------------------------------------------------------
__global__ __launch_bounds__(256)
void gemm_out_kernel(const float* __restrict__ X, const float* __restrict__ W,
                     const float* __restrict__ bias, float* __restrict__ Y)
{
    const int r0 = blockIdx.y * 128;
    const int c0 = blockIdx.x * 64;
    const int tid = threadIdx.x;
    const int ti = tid >> 4;
    const int tj = tid & 15;

    __shared__ __align__(16) float As[16][136];
    __shared__ __align__(16) float Bs[16][68];

    float acc[8][4];
#pragma unroll
    for (int r = 0; r < 8; r++)
#pragma unroll
        for (int c = 0; c < 4; c++) acc[r][c] = 0.f;

    for (int k0 = 0; k0 < 512; k0 += 16) {
        {
            int kk = tid & 15, ibase = tid >> 4;
#pragma unroll
            for (int p = 0; p < 8; p++) {
                int i = ibase + p * 16;
                As[kk][i] = X[(size_t)(r0 + i) * 512 + k0 + kk];
            }
            int j = tid & 63, kb = tid >> 6;
#pragma unroll
            for (int p = 0; p < 4; p++) {
                int kk2 = kb + p * 4;
                Bs[kk2][j] = W[(size_t)(k0 + kk2) * 512 + c0 + j];
            }
        }
        __syncthreads();
#pragma unroll
        for (int kk = 0; kk < 16; kk++) {
            f32x4 a0 = *(const f32x4*)&As[kk][ti * 8];
            f32x4 a1 = *(const f32x4*)&As[kk][ti * 8 + 4];
            f32x4 b0 = *(const f32x4*)&Bs[kk][tj * 4];
#pragma unroll
            for (int r = 0; r < 4; r++)
#pragma unroll
                for (int c = 0; c < 4; c++) {
                    acc[r][c]     = fmaf(a0[r], b0[c], acc[r][c]);
                    acc[r + 4][c] = fmaf(a1[r], b0[c], acc[r + 4][c]);
                }
        }
        __syncthreads();
    }

#pragma unroll
    for (int r = 0; r < 8; r++) {
        size_t row = r0 + ti * 8 + r;
#pragma unroll
        for (int c = 0; c < 4; c++) {
            int col = c0 + tj * 4 + c;
            Y[row * 512 + col] = acc[r][c] + bias[col];
        }
    }
}

// ---------------------------------------------------------------------------
extern "C" void kernel_launch(void* const* d_in, const int* in_sizes, int n_in,
                              void* d_out, int out_size, void* d_ws, size_t ws_size,
                              hipStream_t stream)
{
    const float* query = (const float*)d_in[0];
    const float* key   = (const float*)d_in[1];
    const float* value = (const float*)d_in[2];
    const float* pemb  = (const float*)d_in[3];
    const float* Wq    = (const float*)d_in[4];
    const float* bq    = (const float*)d_in[5];
    const float* Wk    = (const float*)d_in[6];
    const float* bk    = (const float*)d_in[7];
    const float* Wv    = (const float*)d_in[8];
    const float* bv    = (const float*)d_in[9];
    const float* Wpos  = (const float*)d_in[10];
    const float* pbu   = (const float*)d_in[11];
    const float* pbv   = (const float*)d_in[12];
    const float* Wo    = (const float*)d_in[13];
    const float* bo    = (const float*)d_in[14];

    const size_t NE = (size_t)Bb * Hh * Tt * Dd;  // 4,194,304 per tensor
    bf16_t* QU  = (bf16_t*)d_ws;
    bf16_t* QV  = QU + NE;
    bf16_t* K16 = QV + NE;
    bf16_t* V16 = K16 + NE;
    bf16_t* P16 = V16 + NE;
    float*  CTX = (float*)(P16 + NE);             // needs ws >= 56 MB total

    proj_kernel<<<dim3(8, 64, 4), 256, 0, stream>>>(
        query, key, value, pemb, Wq, Wk, Wv, Wpos, bq, bk, bv, pbu, pbv,
        QU, QV, K16, V16, P16);

    attn_kernel<<<dim3(32, 32), 256, 0, stream>>>(QU, QV, K16, V16, P16, CTX);

    gemm_out_kernel<<<dim3(8, 64), 256, 0, stream>>>(CTX, Wo, bo, (float*)d_out);
}

// Round 2
// 783.716 us; speedup vs baseline: 1.3222x; 1.3222x over previous
//
#include <hip/hip_runtime.h>

// ---------------------------------------------------------------------------
// RelPositionMultiHeadedAttention (Conformer / Transformer-XL rel-shift)
// B=4, T=2048, C=512, H=8, D=64
//
// R1 changes (attn_kernel only):
//  - LDS 104.9KB -> 58.6KB: ms_s fp32->bf16, w_s aliased into ms strip
//    (wave-private), q-staging aliased under p_s. => 2 blocks/CU.
//  - vT transpose staging j-major (kills structural 8-way bank conflict).
//  - 4 -> 2 __syncthreads per j-tile (ms/w are wave-private).
// ---------------------------------------------------------------------------

#define Bb 4
#define Tt 2048
#define Cc 512
#define Hh 8
#define Dd 64

typedef __bf16 bf16_t;
typedef __bf16 bf16x8 __attribute__((ext_vector_type(8)));
typedef float  f32x4  __attribute__((ext_vector_type(4)));

// ---------------------------------------------------------------------------
// Kernel 1: fused QKVP projections, fp32. BM=128, BN=64, BK=16, 256 thr,
// 8x4 microtile. z selects which projection.
// ---------------------------------------------------------------------------
__global__ __launch_bounds__(256)
void proj_kernel(const float* __restrict__ Xq, const float* __restrict__ Xk,
                 const float* __restrict__ Xv, const float* __restrict__ Xp,
                 const float* __restrict__ Wq, const float* __restrict__ Wk,
                 const float* __restrict__ Wv, const float* __restrict__ Wp,
                 const float* __restrict__ bq, const float* __restrict__ bk,
                 const float* __restrict__ bv,
                 const float* __restrict__ bias_u, const float* __restrict__ bias_v,
                 bf16_t* __restrict__ QU, bf16_t* __restrict__ QV,
                 bf16_t* __restrict__ K16, bf16_t* __restrict__ V16,
                 bf16_t* __restrict__ P16)
{
    const int z = blockIdx.z;
    const float* X    = (z == 0) ? Xq : (z == 1) ? Xk : (z == 2) ? Xv : Xp;
    const float* W    = (z == 0) ? Wq : (z == 1) ? Wk : (z == 2) ? Wv : Wp;
    const float* bias = (z == 0) ? bq : (z == 1) ? bk : (z == 2) ? bv : nullptr;

    const int r0 = blockIdx.y * 128;
    const int c0 = blockIdx.x * 64;
    const int tid = threadIdx.x;
    const int ti = tid >> 4;
    const int tj = tid & 15;

    __shared__ __align__(16) float As[16][136];
    __shared__ __align__(16) float Bs[16][68];

    float acc[8][4];
#pragma unroll
    for (int r = 0; r < 8; r++)
#pragma unroll
        for (int c = 0; c < 4; c++) acc[r][c] = 0.f;

    for (int k0 = 0; k0 < 512; k0 += 16) {
        {
            int kk = tid & 15, ibase = tid >> 4;
#pragma unroll
            for (int p = 0; p < 8; p++) {
                int i = ibase + p * 16;
                As[kk][i] = X[(size_t)(r0 + i) * 512 + k0 + kk];
            }
            int j = tid & 63, kb = tid >> 6;
#pragma unroll
            for (int p = 0; p < 4; p++) {
                int kk2 = kb + p * 4;
                Bs[kk2][j] = W[(size_t)(k0 + kk2) * 512 + c0 + j];
            }
        }
        __syncthreads();
#pragma unroll
        for (int kk = 0; kk < 16; kk++) {
            f32x4 a0 = *(const f32x4*)&As[kk][ti * 8];
            f32x4 a1 = *(const f32x4*)&As[kk][ti * 8 + 4];
            f32x4 b0 = *(const f32x4*)&Bs[kk][tj * 4];
#pragma unroll
            for (int r = 0; r < 4; r++)
#pragma unroll
                for (int c = 0; c < 4; c++) {
                    acc[r][c]     = fmaf(a0[r], b0[c], acc[r][c]);
                    acc[r + 4][c] = fmaf(a1[r], b0[c], acc[r + 4][c]);
                }
        }
        __syncthreads();
    }

#pragma unroll
    for (int r = 0; r < 8; r++) {
        int row = r0 + ti * 8 + r;
        int b = row >> 11, t = row & 2047;
#pragma unroll
        for (int c = 0; c < 4; c++) {
            int col = c0 + tj * 4 + c;
            int h = col >> 6, d = col & 63;
            float y = acc[r][c] + (bias ? bias[col] : 0.f);
            size_t idx = (((size_t)(b * Hh + h)) * Tt + t) * Dd + d;
            if (z == 0) {
                QU[idx] = (bf16_t)(y + bias_u[col]);
                QV[idx] = (bf16_t)(y + bias_v[col]);
            } else if (z == 1) {
                K16[idx] = (bf16_t)y;
            } else if (z == 2) {
                V16[idx] = (bf16_t)y;
            } else {
                P16[idx] = (bf16_t)y;
            }
        }
    }
}

// ---------------------------------------------------------------------------
// Kernel 2: attention. 64 q-rows/block (4 waves x 16-row strips), j-tiles of
// 64, online softmax, bf16 MFMA 16x16x32. LDS 58.6KB -> 2 blocks/CU.
// ---------------------------------------------------------------------------
// LDS map (bytes):
//   [0,      20736)  region A: preamble qu rows 0..63, qv rows 64..128;
//                    then p band tiles [144][72]
//   [20736,  29952)  k_s  [64][72]
//   [29952,  39168)  vT_s [64][72]
//   [39168,  58624)  msw  [64][152] bf16: per-wave strips (rows wave*16..+15);
//                    band matmul out (cols 0..143), then softmax weights
//                    clobber cols 0..63 (strictly after the gather reads)
__global__ __launch_bounds__(256, 2)
void attn_kernel(const bf16_t* __restrict__ QU, const bf16_t* __restrict__ QV,
                 const bf16_t* __restrict__ K16, const bf16_t* __restrict__ V16,
                 const bf16_t* __restrict__ P16, float* __restrict__ CTX)
{
    const int i0 = blockIdx.x * 64;
    const int bh = blockIdx.y;
    const int b = bh >> 3, h = bh & 7;
    const int tid = threadIdx.x;
    const int wave = tid >> 6;
    const int lane = tid & 63;
    const int quad = lane >> 4;
    const int l16 = lane & 15;

    const size_t hb = (size_t)bh * Tt * Dd;
    const bf16_t* qu_g = QU + hb;
    const bf16_t* qv_g = QV + hb;
    const bf16_t* k_g  = K16 + hb;
    const bf16_t* v_g  = V16 + hb;
    const bf16_t* p_g  = P16 + hb;

    __shared__ __align__(16) char smem[58624];
    bf16_t (*pA)[72]   = (bf16_t (*)[72])(smem);           // 144 rows
    bf16_t (*k_s)[72]  = (bf16_t (*)[72])(smem + 20736);   // 64 rows
    bf16_t (*vT_s)[72] = (bf16_t (*)[72])(smem + 29952);   // 64 rows [d][j]
    bf16_t (*msw)[152] = (bf16_t (*)[152])(smem + 39168);  // 64 rows

    // preamble: stage qu (A rows 0..63), qv (A rows 64..128, clamped)
    for (int idx = tid; idx < 64 * 8; idx += 256) {
        int row = idx >> 3, seg = idx & 7;
        *(f32x4*)&pA[row][seg * 8] = *(const f32x4*)(qu_g + (size_t)(i0 + row) * Dd + seg * 8);
    }
    for (int idx = tid; idx < 65 * 8; idx += 256) {
        int row = idx >> 3, seg = idx & 7;
        int gr = i0 + row; if (gr > Tt - 1) gr = Tt - 1;  // clamped row never gathered
        *(f32x4*)&pA[64 + row][seg * 8] = *(const f32x4*)(qv_g + (size_t)gr * Dd + seg * 8);
    }
    __syncthreads();

    // A-operand fragments: lane holds A[m=l16][k=quad*8+e], k-chunks of 32
    bf16x8 aq[2], av1[2], av2[2];
#pragma unroll
    for (int kc = 0; kc < 2; kc++) {
        aq[kc]  = *(const bf16x8*)&pA[wave * 16 + l16][kc * 32 + quad * 8];
        av1[kc] = *(const bf16x8*)&pA[64 + wave * 16 + l16][kc * 32 + quad * 8];
        av2[kc] = *(const bf16x8*)&pA[64 + wave * 16 + l16 + 1][kc * 32 + quad * 8];
    }
    __syncthreads();  // q region about to be reused for p band

    float mrow[4], lrow[4];
    f32x4 accO[4];
#pragma unroll
    for (int r = 0; r < 4; r++) { mrow[r] = -1e30f; lrow[r] = 0.f; }
#pragma unroll
    for (int dt = 0; dt < 4; dt++)
#pragma unroll
        for (int r = 0; r < 4; r++) accO[dt][r] = 0.f;

    for (int j0 = 0; j0 < Tt; j0 += 64) {
        // band parameters (d = ig - jg over the tile)
        int d_lo = i0 - (j0 + 63);
        int d_hi = i0 + 63 - j0;
        int w1 = 0, prow1 = 0;
        if (d_hi >= 0) {
            int b1 = d_lo > 0 ? d_lo : 0;
            w1 = d_hi - b1 + 1;
            prow1 = (Tt - 1) - d_hi;             // p rows [prow1, prow1+w1)
        }
        int dmax2 = d_hi < -2 ? d_hi : -2;
        int w2 = 0, e_lo = 0;
        if (d_lo <= dmax2) {
            e_lo = -dmax2 - 2;
            int e_hi = -d_lo - 2;
            w2 = e_hi - e_lo + 1;                // p rows [e_lo, e_lo+w2)
        }
        int w1pad = (w1 + 15) & ~15;
        int w2pad = (w2 + 15) & ~15;
        int nct1 = w1pad >> 4;
        int nct  = nct1 + (w2pad >> 4);

        // stage K tile (coalesced 16B)
        for (int idx = tid; idx < 64 * 8; idx += 256) {
            int row = idx >> 3, seg = idx & 7;
            *(f32x4*)&k_s[row][seg * 8] = *(const f32x4*)(k_g + (size_t)(j0 + row) * Dd + seg * 8);
        }
        // stage V tile transposed, j-major lanes (conflict-free LDS writes)
        for (int idx = tid; idx < 64 * 8; idx += 256) {
            int j = idx & 63, seg = idx >> 6;   // seg is wave-uniform
            bf16x8 tmp = *(const bf16x8*)(v_g + (size_t)(j0 + j) * Dd + seg * 8);
#pragma unroll
            for (int e = 0; e < 8; e++) vT_s[seg * 8 + e][j] = tmp[e];
        }
        // stage p bands into region A: [0,w1) <- p[prow1..], [w1pad,..+w2) <- p[e_lo..]
        for (int idx = tid; idx < (w1 + w2) * 8; idx += 256) {
            int rr = idx >> 3, seg = idx & 7;
            int dstrow, srcrow;
            if (rr < w1) { dstrow = rr;                 srcrow = prow1 + rr; }
            else         { dstrow = w1pad + (rr - w1);  srcrow = e_lo + (rr - w1); }
            *(f32x4*)&pA[dstrow][seg * 8] = *(const f32x4*)(p_g + (size_t)srcrow * Dd + seg * 8);
        }
        __syncthreads();

        // content scores: S[16x64] per wave
        f32x4 accS[4];
#pragma unroll
        for (int nt = 0; nt < 4; nt++) {
            f32x4 acc = {0.f, 0.f, 0.f, 0.f};
#pragma unroll
            for (int kc = 0; kc < 2; kc++) {
                bf16x8 bk8 = *(const bf16x8*)&k_s[nt * 16 + l16][kc * 32 + quad * 8];
                acc = __builtin_amdgcn_mfma_f32_16x16x32_bf16(aq[kc], bk8, acc, 0, 0, 0);
            }
            accS[nt] = acc;
        }

        // banded pos matmul -> own msw strip (wave-private, no barrier needed)
        for (int ct = 0; ct < nct; ct++) {
            f32x4 acc = {0.f, 0.f, 0.f, 0.f};
            const bf16x8* A = (ct < nct1) ? av1 : av2;  // band2 uses q_{i+1}
#pragma unroll
            for (int kc = 0; kc < 2; kc++) {
                bf16x8 bp = *(const bf16x8*)&pA[ct * 16 + l16][kc * 32 + quad * 8];
                acc = __builtin_amdgcn_mfma_f32_16x16x32_bf16(A[kc], bp, acc, 0, 0, 0);
            }
#pragma unroll
            for (int r = 0; r < 4; r++)
                msw[wave * 16 + quad * 4 + r][ct * 16 + l16] = (bf16_t)acc[r];
        }

        // gather pos + scale (reads own strip only)
        float sc[4][4];
#pragma unroll
        for (int nt = 0; nt < 4; nt++) {
            int jg = j0 + nt * 16 + l16;
#pragma unroll
            for (int r = 0; r < 4; r++) {
                int il = wave * 16 + quad * 4 + r;
                int ig = i0 + il;
                int dd = ig - jg;
                float pos;
                if (dd >= 0)       pos = (float)msw[il][d_hi - dd];                // (q_i+v)·p[T-1-dd]
                else if (dd == -1) pos = 0.f;                                      // shift zero column
                else               pos = (float)msw[il][w1pad + (-dd - 2 - e_lo)]; // (q_{i+1}+v)·p[jg-ig-2]
                sc[nt][r] = (accS[nt][r] + pos) * 0.125f;
            }
        }

        // online softmax; weights clobber own strip cols 0..63 (after gather)
#pragma unroll
        for (int r = 0; r < 4; r++) {
            float mx = fmaxf(fmaxf(sc[0][r], sc[1][r]), fmaxf(sc[2][r], sc[3][r]));
#pragma unroll
            for (int off = 1; off < 16; off <<= 1) mx = fmaxf(mx, __shfl_xor(mx, off, 64));
            float mnew = fmaxf(mrow[r], mx);
            float alpha = __expf(mrow[r] - mnew);
            mrow[r] = mnew;
            float rsum = 0.f;
#pragma unroll
            for (int nt = 0; nt < 4; nt++) {
                float w = __expf(sc[nt][r] - mnew);
                sc[nt][r] = w;
                rsum += w;
            }
#pragma unroll
            for (int off = 1; off < 16; off <<= 1) rsum += __shfl_xor(rsum, off, 64);
            lrow[r] = lrow[r] * alpha + rsum;
#pragma unroll
            for (int dt = 0; dt < 4; dt++) accO[dt][r] *= alpha;
            int il = wave * 16 + quad * 4 + r;
#pragma unroll
            for (int nt = 0; nt < 4; nt++)
                msw[il][nt * 16 + l16] = (bf16_t)sc[nt][r];
        }

        // O += W @ V   (A = weights from own strip, B = V^T)
#pragma unroll
        for (int kc = 0; kc < 2; kc++) {
            bf16x8 aw = *(const bf16x8*)&msw[wave * 16 + l16][kc * 32 + quad * 8];
#pragma unroll
            for (int dt = 0; dt < 4; dt++) {
                bf16x8 bv8 = *(const bf16x8*)&vT_s[dt * 16 + l16][kc * 32 + quad * 8];
                accO[dt] = __builtin_amdgcn_mfma_f32_16x16x32_bf16(aw, bv8, accO[dt], 0, 0, 0);
            }
        }
        __syncthreads();  // protect k_s/vT_s/pA before next staging
    }

    // epilogue: O / l -> ctx [B,T,C]
#pragma unroll
    for (int r = 0; r < 4; r++) {
        int il = wave * 16 + quad * 4 + r;
        int ig = i0 + il;
        float inv = 1.0f / lrow[r];
#pragma unroll
        for (int dt = 0; dt < 4; dt++) {
            CTX[((size_t)(b * Tt + ig)) * Cc + h * Dd + dt * 16 + l16] = accO[dt][r] * inv;
        }
    }
}

// ---------------------------------------------------------------------------
// Kernel 3: output projection, fp32 (precision-critical).
// ---------------------------------------------------------------------------
__global__ __launch_bounds__(256)
void gemm_out_kernel(const float* __restrict__ X, const float* __restrict__ W,
                     const float* __restrict__ bias, float* __restrict__ Y)
{
    const int r0 = blockIdx.y * 128;
    const int c0 = blockIdx.x * 64;
    const int tid = threadIdx.x;
    const int ti = tid >> 4;
    const int tj = tid & 15;

    __shared__ __align__(16) float As[16][136];
    __shared__ __align__(16) float Bs[16][68];

    float acc[8][4];
#pragma unroll
    for (int r = 0; r < 8; r++)
#pragma unroll
        for (int c = 0; c < 4; c++) acc[r][c] = 0.f;

    for (int k0 = 0; k0 < 512; k0 += 16) {
        {
            int kk = tid & 15, ibase = tid >> 4;
#pragma unroll
            for (int p = 0; p < 8; p++) {
                int i = ibase + p * 16;
                As[kk][i] = X[(size_t)(r0 + i) * 512 + k0 + kk];
            }
            int j = tid & 63, kb = tid >> 6;
#pragma unroll
            for (int p = 0; p < 4; p++) {
                int kk2 = kb + p * 4;
                Bs[kk2][j] = W[(size_t)(k0 + kk2) * 512 + c0 + j];
            }
        }
        __syncthreads();
#pragma unroll
        for (int kk = 0; kk < 16; kk++) {
            f32x4 a0 = *(const f32x4*)&As[kk][ti * 8];
            f32x4 a1 = *(const f32x4*)&As[kk][ti * 8 + 4];
            f32x4 b0 = *(const f32x4*)&Bs[kk][tj * 4];
#pragma unroll
            for (int r = 0; r < 4; r++)
#pragma unroll
                for (int c = 0; c < 4; c++) {
                    acc[r][c]     = fmaf(a0[r], b0[c], acc[r][c]);
                    acc[r + 4][c] = fmaf(a1[r], b0[c], acc[r + 4][c]);
                }
        }
        __syncthreads();
    }

#pragma unroll
    for (int r = 0; r < 8; r++) {
        size_t row = r0 + ti * 8 + r;
#pragma unroll
        for (int c = 0; c < 4; c++) {
            int col = c0 + tj * 4 + c;
            Y[row * 512 + col] = acc[r][c] + bias[col];
        }
    }
}

// ---------------------------------------------------------------------------
extern "C" void kernel_launch(void* const* d_in, const int* in_sizes, int n_in,
                              void* d_out, int out_size, void* d_ws, size_t ws_size,
                              hipStream_t stream)
{
    const float* query = (const float*)d_in[0];
    const float* key   = (const float*)d_in[1];
    const float* value = (const float*)d_in[2];
    const float* pemb  = (const float*)d_in[3];
    const float* Wq    = (const float*)d_in[4];
    const float* bq    = (const float*)d_in[5];
    const float* Wk    = (const float*)d_in[6];
    const float* bk    = (const float*)d_in[7];
    const float* Wv    = (const float*)d_in[8];
    const float* bv    = (const float*)d_in[9];
    const float* Wpos  = (const float*)d_in[10];
    const float* pbu   = (const float*)d_in[11];
    const float* pbv   = (const float*)d_in[12];
    const float* Wo    = (const float*)d_in[13];
    const float* bo    = (const float*)d_in[14];

    const size_t NE = (size_t)Bb * Hh * Tt * Dd;  // 4,194,304 per tensor
    bf16_t* QU  = (bf16_t*)d_ws;
    bf16_t* QV  = QU + NE;
    bf16_t* K16 = QV + NE;
    bf16_t* V16 = K16 + NE;
    bf16_t* P16 = V16 + NE;
    float*  CTX = (float*)(P16 + NE);             // ws >= 56 MB

    proj_kernel<<<dim3(8, 64, 4), 256, 0, stream>>>(
        query, key, value, pemb, Wq, Wk, Wv, Wpos, bq, bk, bv, pbu, pbv,
        QU, QV, K16, V16, P16);

    attn_kernel<<<dim3(32, 32), 256, 0, stream>>>(QU, QV, K16, V16, P16, CTX);

    gemm_out_kernel<<<dim3(8, 64), 256, 0, stream>>>(CTX, Wo, bo, (float*)d_out);
}

// Round 4
// 721.958 us; speedup vs baseline: 1.4353x; 1.0855x over previous
//
#include <hip/hip_runtime.h>

// ---------------------------------------------------------------------------
// RelPositionMultiHeadedAttention (Conformer / Transformer-XL rel-shift)
// B=4, T=2048, C=512, H=8, D=64
//
// R4 = R3 design with the gather-skew bug fixed:
//  - gather col = jl + 63 - il with BLOCK-LOCAL il (was missing -wave*16).
//  - exp2 argument clamped at +120 (kills inf->NaN channel on any garbage).
//  - fixed-max softmax (m=12, shift-invariance exact), skewed band layout,
//    per-strip band tile skip, LDS 53KB => 3 blocks/CU.
// ---------------------------------------------------------------------------

#define Bb 4
#define Tt 2048
#define Cc 512
#define Hh 8
#define Dd 64

typedef __bf16 bf16_t;
typedef __bf16 bf16x8 __attribute__((ext_vector_type(8)));
typedef float  f32x4  __attribute__((ext_vector_type(4)));

// ---------------------------------------------------------------------------
// Kernel 1: fused QKVP projections, fp32 (unchanged from R2).
// ---------------------------------------------------------------------------
__global__ __launch_bounds__(256)
void proj_kernel(const float* __restrict__ Xq, const float* __restrict__ Xk,
                 const float* __restrict__ Xv, const float* __restrict__ Xp,
                 const float* __restrict__ Wq, const float* __restrict__ Wk,
                 const float* __restrict__ Wv, const float* __restrict__ Wp,
                 const float* __restrict__ bq, const float* __restrict__ bk,
                 const float* __restrict__ bv,
                 const float* __restrict__ bias_u, const float* __restrict__ bias_v,
                 bf16_t* __restrict__ QU, bf16_t* __restrict__ QV,
                 bf16_t* __restrict__ K16, bf16_t* __restrict__ V16,
                 bf16_t* __restrict__ P16)
{
    const int z = blockIdx.z;
    const float* X    = (z == 0) ? Xq : (z == 1) ? Xk : (z == 2) ? Xv : Xp;
    const float* W    = (z == 0) ? Wq : (z == 1) ? Wk : (z == 2) ? Wv : Wp;
    const float* bias = (z == 0) ? bq : (z == 1) ? bk : (z == 2) ? bv : nullptr;

    const int r0 = blockIdx.y * 128;
    const int c0 = blockIdx.x * 64;
    const int tid = threadIdx.x;
    const int ti = tid >> 4;
    const int tj = tid & 15;

    __shared__ __align__(16) float As[16][136];
    __shared__ __align__(16) float Bs[16][68];

    float acc[8][4];
#pragma unroll
    for (int r = 0; r < 8; r++)
#pragma unroll
        for (int c = 0; c < 4; c++) acc[r][c] = 0.f;

    for (int k0 = 0; k0 < 512; k0 += 16) {
        {
            int kk = tid & 15, ibase = tid >> 4;
#pragma unroll
            for (int p = 0; p < 8; p++) {
                int i = ibase + p * 16;
                As[kk][i] = X[(size_t)(r0 + i) * 512 + k0 + kk];
            }
            int j = tid & 63, kb = tid >> 6;
#pragma unroll
            for (int p = 0; p < 4; p++) {
                int kk2 = kb + p * 4;
                Bs[kk2][j] = W[(size_t)(k0 + kk2) * 512 + c0 + j];
            }
        }
        __syncthreads();
#pragma unroll
        for (int kk = 0; kk < 16; kk++) {
            f32x4 a0 = *(const f32x4*)&As[kk][ti * 8];
            f32x4 a1 = *(const f32x4*)&As[kk][ti * 8 + 4];
            f32x4 b0 = *(const f32x4*)&Bs[kk][tj * 4];
#pragma unroll
            for (int r = 0; r < 4; r++)
#pragma unroll
                for (int c = 0; c < 4; c++) {
                    acc[r][c]     = fmaf(a0[r], b0[c], acc[r][c]);
                    acc[r + 4][c] = fmaf(a1[r], b0[c], acc[r + 4][c]);
                }
        }
        __syncthreads();
    }

#pragma unroll
    for (int r = 0; r < 8; r++) {
        int row = r0 + ti * 8 + r;
        int b = row >> 11, t = row & 2047;
#pragma unroll
        for (int c = 0; c < 4; c++) {
            int col = c0 + tj * 4 + c;
            int h = col >> 6, d = col & 63;
            float y = acc[r][c] + (bias ? bias[col] : 0.f);
            size_t idx = (((size_t)(b * Hh + h)) * Tt + t) * Dd + d;
            if (z == 0) {
                QU[idx] = (bf16_t)(y + bias_u[col]);
                QV[idx] = (bf16_t)(y + bias_v[col]);
            } else if (z == 1) {
                K16[idx] = (bf16_t)y;
            } else if (z == 2) {
                V16[idx] = (bf16_t)y;
            } else {
                P16[idx] = (bf16_t)y;
            }
        }
    }
}

// ---------------------------------------------------------------------------
// Kernel 2: attention.
// LDS map (bytes), total 54272:
//   [0,     18432)  pA   [128][72] bf16: preamble qu rows 0..63 / qv rows
//                   64..128 (row 128 spills into k_s start, pre-loop only);
//                   then p band rows 0..(w1+w2)
//   [18432, 27648)  k_s  [64][72]
//   [27648, 36864)  vT_s [64][72]  ([d][j])
//   [36864, 54272)  msw  [64][136] bf16, wave-private strips:
//                   skewed pos scores at col = jl + 63 - il (block-local il),
//                   cols 0..126; then softmax weights clobber cols 0..63
//                   (strictly after the gathers).
// ---------------------------------------------------------------------------
__global__ __launch_bounds__(256, 3)
void attn_kernel(const bf16_t* __restrict__ QU, const bf16_t* __restrict__ QV,
                 const bf16_t* __restrict__ K16, const bf16_t* __restrict__ V16,
                 const bf16_t* __restrict__ P16, float* __restrict__ CTX)
{
    const int i0 = blockIdx.x * 64;
    const int bh = blockIdx.y;
    const int b = bh >> 3, h = bh & 7;
    const int tid = threadIdx.x;
    const int wave = tid >> 6;
    const int lane = tid & 63;
    const int quad = lane >> 4;
    const int l16 = lane & 15;

    const size_t hb = (size_t)bh * Tt * Dd;
    const bf16_t* qu_g = QU + hb;
    const bf16_t* qv_g = QV + hb;
    const bf16_t* k_g  = K16 + hb;
    const bf16_t* v_g  = V16 + hb;
    const bf16_t* p_g  = P16 + hb;

    __shared__ __align__(16) char smem[54272];
    bf16_t (*pA)[72]   = (bf16_t (*)[72])(smem);           // 128 rows
    bf16_t (*k_s)[72]  = (bf16_t (*)[72])(smem + 18432);   // 64 rows
    bf16_t (*vT_s)[72] = (bf16_t (*)[72])(smem + 27648);   // 64 rows [d][j]
    bf16_t (*msw)[136] = (bf16_t (*)[136])(smem + 36864);  // 64 rows

    // preamble: qu -> pA rows 0..63 ; qv -> pA rows 64..128 (clamped; row 128
    // = k_s[0] byte-contiguously, consumed before k_s is first staged)
    for (int idx = tid; idx < 64 * 8; idx += 256) {
        int row = idx >> 3, seg = idx & 7;
        *(f32x4*)&pA[row][seg * 8] = *(const f32x4*)(qu_g + (size_t)(i0 + row) * Dd + seg * 8);
    }
    for (int idx = tid; idx < 65 * 8; idx += 256) {
        int row = idx >> 3, seg = idx & 7;
        int gr = i0 + row; if (gr > Tt - 1) gr = Tt - 1;  // clamped row never gathered
        *(f32x4*)&pA[64 + row][seg * 8] = *(const f32x4*)(qv_g + (size_t)gr * Dd + seg * 8);
    }
    __syncthreads();

    // A-operand fragments: lane holds A[m=l16][k=quad*8+e], k-chunks of 32
    bf16x8 aq[2], av1[2], av2[2];
#pragma unroll
    for (int kc = 0; kc < 2; kc++) {
        aq[kc]  = *(const bf16x8*)&pA[wave * 16 + l16][kc * 32 + quad * 8];
        av1[kc] = *(const bf16x8*)&pA[64 + wave * 16 + l16][kc * 32 + quad * 8];
        av2[kc] = *(const bf16x8*)&pA[64 + wave * 16 + l16 + 1][kc * 32 + quad * 8];
    }
    __syncthreads();  // q region about to be reused for p band

    float lsum[4];
    f32x4 accO[4];
#pragma unroll
    for (int r = 0; r < 4; r++) lsum[r] = 0.f;
#pragma unroll
    for (int dt = 0; dt < 4; dt++)
#pragma unroll
        for (int r = 0; r < 4; r++) accO[dt][r] = 0.f;

    // strip's gathered-column window: col = jl + 63 - il, il in
    // [wave*16, wave*16+15], jl in [0,63] -> [48-wave*16, 126-wave*16]
    const int cmin = 48 - wave * 16;
    const int cmax = 126 - wave * 16;

    for (int j0 = 0; j0 < Tt; j0 += 64) {
        // band parameters (dd = ig - jg over the tile)
        int d_lo = i0 - (j0 + 63);
        int d_hi = i0 + 63 - j0;
        int w1 = 0, prow1 = 0;
        if (d_hi >= 0) {
            int b1 = d_lo > 0 ? d_lo : 0;
            w1 = d_hi - b1 + 1;                  // band1: dd in [max(d_lo,0), d_hi]
            prow1 = (Tt - 1) - d_hi;             // p rows [prow1, prow1+w1) = cols [0,w1)
        }
        int dmax2 = d_hi < -2 ? d_hi : -2;
        int w2 = 0, e_lo = 0;
        if (d_lo <= dmax2) {
            e_lo = -dmax2 - 2;
            int e_hi = -d_lo - 2;
            w2 = e_hi - e_lo + 1;                // band2: p rows [e_lo, e_lo+w2)
        }
        int c2_0 = d_hi + 2 + e_lo;              // first band2 column
        int nct1 = (w1 + 15) >> 4;
        int nct2 = (w2 + 15) >> 4;

        // stage K tile
        for (int idx = tid; idx < 64 * 8; idx += 256) {
            int row = idx >> 3, seg = idx & 7;
            *(f32x4*)&k_s[row][seg * 8] = *(const f32x4*)(k_g + (size_t)(j0 + row) * Dd + seg * 8);
        }
        // stage V tile transposed, j-major lanes
        for (int idx = tid; idx < 64 * 8; idx += 256) {
            int j = idx & 63, seg = idx >> 6;
            bf16x8 tmp = *(const bf16x8*)(v_g + (size_t)(j0 + j) * Dd + seg * 8);
#pragma unroll
            for (int e = 0; e < 8; e++) vT_s[seg * 8 + e][j] = tmp[e];
        }
        // stage p bands contiguously: rows [0,w1) band1, rows [w1,w1+w2) band2
        for (int idx = tid; idx < (w1 + w2) * 8; idx += 256) {
            int rr = idx >> 3, seg = idx & 7;
            int srcrow = (rr < w1) ? (prow1 + rr) : (e_lo + rr - w1);
            *(f32x4*)&pA[rr][seg * 8] = *(const f32x4*)(p_g + (size_t)srcrow * Dd + seg * 8);
        }
        __syncthreads();

        // content scores: S[16x64] per wave
        f32x4 accS[4];
#pragma unroll
        for (int nt = 0; nt < 4; nt++) {
            f32x4 acc = {0.f, 0.f, 0.f, 0.f};
#pragma unroll
            for (int kc = 0; kc < 2; kc++) {
                bf16x8 bk8 = *(const bf16x8*)&k_s[nt * 16 + l16][kc * 32 + quad * 8];
                acc = __builtin_amdgcn_mfma_f32_16x16x32_bf16(aq[kc], bk8, acc, 0, 0, 0);
            }
            accS[nt] = acc;
        }

        // banded pos matmul -> skewed store into own strip (wave-private).
        // band1 tile ct: cols [16ct,16ct+16); band2 tile u: cols [c2_0+16u,..)
        for (int ct = 0; ct < nct1 + nct2; ct++) {
            bool b2 = ct >= nct1;
            int rb = b2 ? (w1 + (ct - nct1) * 16) : (ct * 16);
            int cb = b2 ? (c2_0 + (ct - nct1) * 16) : (ct * 16);
            if (cb > cmax || cb + 15 < cmin) continue;   // strip doesn't need it
            f32x4 acc = {0.f, 0.f, 0.f, 0.f};
#pragma unroll
            for (int kc = 0; kc < 2; kc++) {
                bf16x8 bp = *(const bf16x8*)&pA[rb + l16][kc * 32 + quad * 8];
                acc = b2 ? __builtin_amdgcn_mfma_f32_16x16x32_bf16(av2[kc], bp, acc, 0, 0, 0)
                         : __builtin_amdgcn_mfma_f32_16x16x32_bf16(av1[kc], bp, acc, 0, 0, 0);
            }
            int col = cb + l16;
            if (col < 128) {
#pragma unroll
                for (int r = 0; r < 4; r++)
                    msw[wave * 16 + quad * 4 + r][col] = (bf16_t)acc[r];
            }
        }
        // zero column for dd == -1 (after band writes, before gather)
        {
            int zc = d_hi + 1;
            if ((unsigned)zc < 128u && quad == 0)
                msw[wave * 16 + l16][zc] = (bf16_t)0.f;
        }

        // gather (branchless skewed read, BLOCK-LOCAL il) + fixed-max exp;
        // weights clobber own strip cols 0..63 (strictly after gathers)
#pragma unroll
        for (int nt = 0; nt < 4; nt++) {
#pragma unroll
            for (int r = 0; r < 4; r++) {
                int il = wave * 16 + quad * 4 + r;
                float pos = (float)msw[il][nt * 16 + l16 + 63 - il];
                float x = accS[nt][r] + pos;
                // exp((x/8) - 12) = 2^(x*0.18033688 - 17.3123405); clamp kills
                // any inf->NaN channel from residual garbage.
                float a = fminf(fmaf(x, 0.18033688f, -17.3123405f), 120.0f);
                float w = exp2f(a);
                lsum[r] += w;
                msw[il][nt * 16 + l16] = (bf16_t)w;
            }
        }

        // O += W @ V   (A = weights from own strip, B = V^T)
#pragma unroll
        for (int kc = 0; kc < 2; kc++) {
            bf16x8 aw = *(const bf16x8*)&msw[wave * 16 + l16][kc * 32 + quad * 8];
#pragma unroll
            for (int dt = 0; dt < 4; dt++) {
                bf16x8 bv8 = *(const bf16x8*)&vT_s[dt * 16 + l16][kc * 32 + quad * 8];
                accO[dt] = __builtin_amdgcn_mfma_f32_16x16x32_bf16(aw, bv8, accO[dt], 0, 0, 0);
            }
        }
        __syncthreads();  // protect k_s/vT_s/pA before next staging
    }

    // single end-of-kernel row-sum reduction (16 lanes per quad-row)
#pragma unroll
    for (int r = 0; r < 4; r++) {
#pragma unroll
        for (int off = 1; off < 16; off <<= 1) lsum[r] += __shfl_xor(lsum[r], off, 64);
    }

    // epilogue: O / l -> ctx [B,T,C]
#pragma unroll
    for (int r = 0; r < 4; r++) {
        int il = wave * 16 + quad * 4 + r;
        int ig = i0 + il;
        float inv = 1.0f / lsum[r];
#pragma unroll
        for (int dt = 0; dt < 4; dt++) {
            CTX[((size_t)(b * Tt + ig)) * Cc + h * Dd + dt * 16 + l16] = accO[dt][r] * inv;
        }
    }
}

// ---------------------------------------------------------------------------
// Kernel 3: output projection, fp32 (precision-critical, unchanged).
// ---------------------------------------------------------------------------
__global__ __launch_bounds__(256)
void gemm_out_kernel(const float* __restrict__ X, const float* __restrict__ W,
                     const float* __restrict__ bias, float* __restrict__ Y)
{
    const int r0 = blockIdx.y * 128;
    const int c0 = blockIdx.x * 64;
    const int tid = threadIdx.x;
    const int ti = tid >> 4;
    const int tj = tid & 15;

    __shared__ __align__(16) float As[16][136];
    __shared__ __align__(16) float Bs[16][68];

    float acc[8][4];
#pragma unroll
    for (int r = 0; r < 8; r++)
#pragma unroll
        for (int c = 0; c < 4; c++) acc[r][c] = 0.f;

    for (int k0 = 0; k0 < 512; k0 += 16) {
        {
            int kk = tid & 15, ibase = tid >> 4;
#pragma unroll
            for (int p = 0; p < 8; p++) {
                int i = ibase + p * 16;
                As[kk][i] = X[(size_t)(r0 + i) * 512 + k0 + kk];
            }
            int j = tid & 63, kb = tid >> 6;
#pragma unroll
            for (int p = 0; p < 4; p++) {
                int kk2 = kb + p * 4;
                Bs[kk2][j] = W[(size_t)(k0 + kk2) * 512 + c0 + j];
            }
        }
        __syncthreads();
#pragma unroll
        for (int kk = 0; kk < 16; kk++) {
            f32x4 a0 = *(const f32x4*)&As[kk][ti * 8];
            f32x4 a1 = *(const f32x4*)&As[kk][ti * 8 + 4];
            f32x4 b0 = *(const f32x4*)&Bs[kk][tj * 4];
#pragma unroll
            for (int r = 0; r < 4; r++)
#pragma unroll
                for (int c = 0; c < 4; c++) {
                    acc[r][c]     = fmaf(a0[r], b0[c], acc[r][c]);
                    acc[r + 4][c] = fmaf(a1[r], b0[c], acc[r + 4][c]);
                }
        }
        __syncthreads();
    }

#pragma unroll
    for (int r = 0; r < 8; r++) {
        size_t row = r0 + ti * 8 + r;
#pragma unroll
        for (int c = 0; c < 4; c++) {
            int col = c0 + tj * 4 + c;
            Y[row * 512 + col] = acc[r][c] + bias[col];
        }
    }
}

// ---------------------------------------------------------------------------
extern "C" void kernel_launch(void* const* d_in, const int* in_sizes, int n_in,
                              void* d_out, int out_size, void* d_ws, size_t ws_size,
                              hipStream_t stream)
{
    const float* query = (const float*)d_in[0];
    const float* key   = (const float*)d_in[1];
    const float* value = (const float*)d_in[2];
    const float* pemb  = (const float*)d_in[3];
    const float* Wq    = (const float*)d_in[4];
    const float* bq    = (const float*)d_in[5];
    const float* Wk    = (const float*)d_in[6];
    const float* bk    = (const float*)d_in[7];
    const float* Wv    = (const float*)d_in[8];
    const float* bv    = (const float*)d_in[9];
    const float* Wpos  = (const float*)d_in[10];
    const float* pbu   = (const float*)d_in[11];
    const float* pbv   = (const float*)d_in[12];
    const float* Wo    = (const float*)d_in[13];
    const float* bo    = (const float*)d_in[14];

    const size_t NE = (size_t)Bb * Hh * Tt * Dd;  // 4,194,304 per tensor
    bf16_t* QU  = (bf16_t*)d_ws;
    bf16_t* QV  = QU + NE;
    bf16_t* K16 = QV + NE;
    bf16_t* V16 = K16 + NE;
    bf16_t* P16 = V16 + NE;
    float*  CTX = (float*)(P16 + NE);             // ws >= 56 MB

    proj_kernel<<<dim3(8, 64, 4), 256, 0, stream>>>(
        query, key, value, pemb, Wq, Wk, Wv, Wpos, bq, bk, bv, pbu, pbv,
        QU, QV, K16, V16, P16);

    attn_kernel<<<dim3(32, 32), 256, 0, stream>>>(QU, QV, K16, V16, P16, CTX);

    gemm_out_kernel<<<dim3(8, 64), 256, 0, stream>>>(CTX, Wo, bo, (float*)d_out);
}

// Round 5
// 640.924 us; speedup vs baseline: 1.6167x; 1.1264x over previous
//
#include <hip/hip_runtime.h>

// ---------------------------------------------------------------------------
// RelPositionMultiHeadedAttention (Conformer / Transformer-XL rel-shift)
// B=4, T=2048, C=512, H=8, D=64
//
// R5 changes:
//  - proj_kernel + gemm_out replaced by ONE split-bf16 MFMA GEMM kernel:
//    X=Xhi+Xlo, W=Whi+Wlo (bf16), C = Xhi·Whi + Xhi·Blo + Alo·Bhi  (~fp32
//    quality, lo·lo dropped ~2^-16 rel). BM=BN=128, BK=64, 4 waves 2x2.
//    XCD swizzle: 4 N-tiles of a row-block -> same XCD (X fetched once).
//  - attn_kernel unchanged from R4 (passed, 330us).
// ---------------------------------------------------------------------------

#define Bb 4
#define Tt 2048
#define Cc 512
#define Hh 8
#define Dd 64

typedef __bf16 bf16_t;
typedef __bf16 bf16x8 __attribute__((ext_vector_type(8)));
typedef float  f32x4  __attribute__((ext_vector_type(4)));

// ---------------------------------------------------------------------------
// Split-bf16 MFMA GEMM: Y = X @ W (+bias). X [8192,512] fp32, W [512,512] fp32.
// mode (modeArg<0 ? blockIdx.z : modeArg): 0=Q(->QU,QV) 1=K 2=V 3=P 4=out.
// ---------------------------------------------------------------------------
__global__ __launch_bounds__(256, 2)
void split_gemm_kernel(const float* __restrict__ Xq, const float* __restrict__ Xk,
                       const float* __restrict__ Xv, const float* __restrict__ Xp,
                       const float* __restrict__ Xc,
                       const float* __restrict__ Wq, const float* __restrict__ Wk,
                       const float* __restrict__ Wv, const float* __restrict__ Wp,
                       const float* __restrict__ Wo,
                       const float* __restrict__ bq, const float* __restrict__ bk,
                       const float* __restrict__ bv, const float* __restrict__ bo,
                       const float* __restrict__ bias_u, const float* __restrict__ bias_v,
                       bf16_t* __restrict__ QU, bf16_t* __restrict__ QV,
                       bf16_t* __restrict__ K16, bf16_t* __restrict__ V16,
                       bf16_t* __restrict__ P16, float* __restrict__ OUT,
                       int modeArg)
{
    const int z = (modeArg < 0) ? blockIdx.z : modeArg;
    const float* X    = (z == 0) ? Xq : (z == 1) ? Xk : (z == 2) ? Xv : (z == 3) ? Xp : Xc;
    const float* W    = (z == 0) ? Wq : (z == 1) ? Wk : (z == 2) ? Wv : (z == 3) ? Wp : Wo;
    const float* bias = (z == 0) ? bq : (z == 1) ? bk : (z == 2) ? bv : (z == 3) ? nullptr : bo;

    // XCD swizzle: bx%8 presumed XCD; all 4 N-tiles of a row-tile share one XCD.
    const int bx = blockIdx.x;
    const int g  = bx >> 3, x8 = bx & 7;
    const int mtile = (g >> 2) * 8 + x8;   // 0..63
    const int ntile = g & 3;               // 0..3
    const int r0 = mtile * 128;
    const int c0 = ntile * 128;

    const int tid  = threadIdx.x;
    const int wave = tid >> 6;
    const int lane = tid & 63;
    const int quad = lane >> 4;
    const int l16  = lane & 15;
    const int rb = (wave >> 1) * 64;       // wave row base within block tile
    const int cb = (wave & 1) * 64;        // wave col base

    __shared__ __align__(16) float Xs[128][68];  // [m][k], stride 68 (b128-friendly)
    __shared__ float Wt[128][65];                // [n][k], odd stride (b32 conflict-free)

    f32x4 acc[4][4];
#pragma unroll
    for (int mt = 0; mt < 4; mt++)
#pragma unroll
        for (int nt = 0; nt < 4; nt++)
#pragma unroll
            for (int r = 0; r < 4; r++) acc[mt][nt][r] = 0.f;

    for (int it = 0; it < 8; ++it) {
        const int k0 = it * 64;
        // stage X tile 128x64 (f32x4, coalesced; 2-way LDS writes = free)
#pragma unroll
        for (int rep = 0; rep < 8; rep++) {
            int id = rep * 256 + tid;            // 0..2047
            int m = id >> 4, c = id & 15;
            f32x4 v = *(const f32x4*)&X[(size_t)(r0 + m) * 512 + k0 + c * 4];
            *(f32x4*)&Xs[m][c * 4] = v;
        }
        // stage W tile 64x128 transposed -> Wt[n][k]
#pragma unroll
        for (int rep = 0; rep < 8; rep++) {
            int id = rep * 256 + tid;
            int cc = id & 31, kk = id >> 5;      // kk 0..63
            f32x4 v = *(const f32x4*)&W[(size_t)(k0 + kk) * 512 + c0 + cc * 4];
#pragma unroll
            for (int i = 0; i < 4; i++) Wt[cc * 4 + i][kk] = v[i];
        }
        __syncthreads();

#pragma unroll
        for (int kc = 0; kc < 2; kc++) {
            // B fragments (hi/lo split)
            bf16x8 Bhi[4], Blo[4];
#pragma unroll
            for (int nt = 0; nt < 4; nt++) {
#pragma unroll
                for (int e = 0; e < 8; e++) {
                    float f = Wt[cb + nt * 16 + l16][kc * 32 + quad * 8 + e];
                    bf16_t hi = (bf16_t)f;
                    Bhi[nt][e] = hi;
                    Blo[nt][e] = (bf16_t)(f - (float)hi);
                }
            }
#pragma unroll
            for (int mt = 0; mt < 4; mt++) {
                f32x4 a0 = *(const f32x4*)&Xs[rb + mt * 16 + l16][kc * 32 + quad * 8];
                f32x4 a1 = *(const f32x4*)&Xs[rb + mt * 16 + l16][kc * 32 + quad * 8 + 4];
                bf16x8 Ahi, Alo;
#pragma unroll
                for (int e = 0; e < 4; e++) {
                    bf16_t h0 = (bf16_t)a0[e];
                    Ahi[e] = h0; Alo[e] = (bf16_t)(a0[e] - (float)h0);
                    bf16_t h1 = (bf16_t)a1[e];
                    Ahi[4 + e] = h1; Alo[4 + e] = (bf16_t)(a1[e] - (float)h1);
                }
#pragma unroll
                for (int nt = 0; nt < 4; nt++) {
                    acc[mt][nt] = __builtin_amdgcn_mfma_f32_16x16x32_bf16(Ahi, Bhi[nt], acc[mt][nt], 0, 0, 0);
                    acc[mt][nt] = __builtin_amdgcn_mfma_f32_16x16x32_bf16(Ahi, Blo[nt], acc[mt][nt], 0, 0, 0);
                    acc[mt][nt] = __builtin_amdgcn_mfma_f32_16x16x32_bf16(Alo, Bhi[nt], acc[mt][nt], 0, 0, 0);
                }
            }
        }
        __syncthreads();
    }

    // epilogue
#pragma unroll
    for (int mt = 0; mt < 4; mt++) {
#pragma unroll
        for (int r = 0; r < 4; r++) {
            int row = r0 + rb + mt * 16 + quad * 4 + r;
#pragma unroll
            for (int nt = 0; nt < 4; nt++) {
                int col = c0 + cb + nt * 16 + l16;
                float y = acc[mt][nt][r] + (bias ? bias[col] : 0.f);
                if (z == 4) {
                    OUT[(size_t)row * 512 + col] = y;
                } else {
                    int b = row >> 11, t = row & 2047;
                    int h = col >> 6,  d = col & 63;
                    size_t idx = (((size_t)(b * Hh + h)) * Tt + t) * Dd + d;
                    if (z == 0) {
                        QU[idx] = (bf16_t)(y + bias_u[col]);
                        QV[idx] = (bf16_t)(y + bias_v[col]);
                    } else if (z == 1) {
                        K16[idx] = (bf16_t)y;
                    } else if (z == 2) {
                        V16[idx] = (bf16_t)y;
                    } else {
                        P16[idx] = (bf16_t)y;
                    }
                }
            }
        }
    }
}

// ---------------------------------------------------------------------------
// Kernel 2: attention (unchanged from R4).
// LDS map (bytes), total 54272:
//   [0,     18432)  pA   [128][72] bf16: preamble qu rows 0..63 / qv rows
//                   64..128 (row 128 spills into k_s start, pre-loop only);
//                   then p band rows 0..(w1+w2)
//   [18432, 27648)  k_s  [64][72]
//   [27648, 36864)  vT_s [64][72]  ([d][j])
//   [36864, 54272)  msw  [64][136] bf16, wave-private strips:
//                   skewed pos scores at col = jl + 63 - il (block-local il),
//                   cols 0..126; then softmax weights clobber cols 0..63
//                   (strictly after the gathers).
// ---------------------------------------------------------------------------
__global__ __launch_bounds__(256, 3)
void attn_kernel(const bf16_t* __restrict__ QU, const bf16_t* __restrict__ QV,
                 const bf16_t* __restrict__ K16, const bf16_t* __restrict__ V16,
                 const bf16_t* __restrict__ P16, float* __restrict__ CTX)
{
    const int i0 = blockIdx.x * 64;
    const int bh = blockIdx.y;
    const int b = bh >> 3, h = bh & 7;
    const int tid = threadIdx.x;
    const int wave = tid >> 6;
    const int lane = tid & 63;
    const int quad = lane >> 4;
    const int l16 = lane & 15;

    const size_t hb = (size_t)bh * Tt * Dd;
    const bf16_t* qu_g = QU + hb;
    const bf16_t* qv_g = QV + hb;
    const bf16_t* k_g  = K16 + hb;
    const bf16_t* v_g  = V16 + hb;
    const bf16_t* p_g  = P16 + hb;

    __shared__ __align__(16) char smem[54272];
    bf16_t (*pA)[72]   = (bf16_t (*)[72])(smem);           // 128 rows
    bf16_t (*k_s)[72]  = (bf16_t (*)[72])(smem + 18432);   // 64 rows
    bf16_t (*vT_s)[72] = (bf16_t (*)[72])(smem + 27648);   // 64 rows [d][j]
    bf16_t (*msw)[136] = (bf16_t (*)[136])(smem + 36864);  // 64 rows

    for (int idx = tid; idx < 64 * 8; idx += 256) {
        int row = idx >> 3, seg = idx & 7;
        *(f32x4*)&pA[row][seg * 8] = *(const f32x4*)(qu_g + (size_t)(i0 + row) * Dd + seg * 8);
    }
    for (int idx = tid; idx < 65 * 8; idx += 256) {
        int row = idx >> 3, seg = idx & 7;
        int gr = i0 + row; if (gr > Tt - 1) gr = Tt - 1;  // clamped row never gathered
        *(f32x4*)&pA[64 + row][seg * 8] = *(const f32x4*)(qv_g + (size_t)gr * Dd + seg * 8);
    }
    __syncthreads();

    bf16x8 aq[2], av1[2], av2[2];
#pragma unroll
    for (int kc = 0; kc < 2; kc++) {
        aq[kc]  = *(const bf16x8*)&pA[wave * 16 + l16][kc * 32 + quad * 8];
        av1[kc] = *(const bf16x8*)&pA[64 + wave * 16 + l16][kc * 32 + quad * 8];
        av2[kc] = *(const bf16x8*)&pA[64 + wave * 16 + l16 + 1][kc * 32 + quad * 8];
    }
    __syncthreads();  // q region about to be reused for p band

    float lsum[4];
    f32x4 accO[4];
#pragma unroll
    for (int r = 0; r < 4; r++) lsum[r] = 0.f;
#pragma unroll
    for (int dt = 0; dt < 4; dt++)
#pragma unroll
        for (int r = 0; r < 4; r++) accO[dt][r] = 0.f;

    const int cmin = 48 - wave * 16;
    const int cmax = 126 - wave * 16;

    for (int j0 = 0; j0 < Tt; j0 += 64) {
        int d_lo = i0 - (j0 + 63);
        int d_hi = i0 + 63 - j0;
        int w1 = 0, prow1 = 0;
        if (d_hi >= 0) {
            int b1 = d_lo > 0 ? d_lo : 0;
            w1 = d_hi - b1 + 1;
            prow1 = (Tt - 1) - d_hi;
        }
        int dmax2 = d_hi < -2 ? d_hi : -2;
        int w2 = 0, e_lo = 0;
        if (d_lo <= dmax2) {
            e_lo = -dmax2 - 2;
            int e_hi = -d_lo - 2;
            w2 = e_hi - e_lo + 1;
        }
        int c2_0 = d_hi + 2 + e_lo;
        int nct1 = (w1 + 15) >> 4;
        int nct2 = (w2 + 15) >> 4;

        for (int idx = tid; idx < 64 * 8; idx += 256) {
            int row = idx >> 3, seg = idx & 7;
            *(f32x4*)&k_s[row][seg * 8] = *(const f32x4*)(k_g + (size_t)(j0 + row) * Dd + seg * 8);
        }
        for (int idx = tid; idx < 64 * 8; idx += 256) {
            int j = idx & 63, seg = idx >> 6;
            bf16x8 tmp = *(const bf16x8*)(v_g + (size_t)(j0 + j) * Dd + seg * 8);
#pragma unroll
            for (int e = 0; e < 8; e++) vT_s[seg * 8 + e][j] = tmp[e];
        }
        for (int idx = tid; idx < (w1 + w2) * 8; idx += 256) {
            int rr = idx >> 3, seg = idx & 7;
            int srcrow = (rr < w1) ? (prow1 + rr) : (e_lo + rr - w1);
            *(f32x4*)&pA[rr][seg * 8] = *(const f32x4*)(p_g + (size_t)srcrow * Dd + seg * 8);
        }
        __syncthreads();

        f32x4 accS[4];
#pragma unroll
        for (int nt = 0; nt < 4; nt++) {
            f32x4 acc = {0.f, 0.f, 0.f, 0.f};
#pragma unroll
            for (int kc = 0; kc < 2; kc++) {
                bf16x8 bk8 = *(const bf16x8*)&k_s[nt * 16 + l16][kc * 32 + quad * 8];
                acc = __builtin_amdgcn_mfma_f32_16x16x32_bf16(aq[kc], bk8, acc, 0, 0, 0);
            }
            accS[nt] = acc;
        }

        for (int ct = 0; ct < nct1 + nct2; ct++) {
            bool b2 = ct >= nct1;
            int rb_ = b2 ? (w1 + (ct - nct1) * 16) : (ct * 16);
            int cb_ = b2 ? (c2_0 + (ct - nct1) * 16) : (ct * 16);
            if (cb_ > cmax || cb_ + 15 < cmin) continue;
            f32x4 acc = {0.f, 0.f, 0.f, 0.f};
#pragma unroll
            for (int kc = 0; kc < 2; kc++) {
                bf16x8 bp = *(const bf16x8*)&pA[rb_ + l16][kc * 32 + quad * 8];
                acc = b2 ? __builtin_amdgcn_mfma_f32_16x16x32_bf16(av2[kc], bp, acc, 0, 0, 0)
                         : __builtin_amdgcn_mfma_f32_16x16x32_bf16(av1[kc], bp, acc, 0, 0, 0);
            }
            int col = cb_ + l16;
            if (col < 128) {
#pragma unroll
                for (int r = 0; r < 4; r++)
                    msw[wave * 16 + quad * 4 + r][col] = (bf16_t)acc[r];
            }
        }
        {
            int zc = d_hi + 1;
            if ((unsigned)zc < 128u && quad == 0)
                msw[wave * 16 + l16][zc] = (bf16_t)0.f;
        }

#pragma unroll
        for (int nt = 0; nt < 4; nt++) {
#pragma unroll
            for (int r = 0; r < 4; r++) {
                int il = wave * 16 + quad * 4 + r;
                float pos = (float)msw[il][nt * 16 + l16 + 63 - il];
                float x = accS[nt][r] + pos;
                float a = fminf(fmaf(x, 0.18033688f, -17.3123405f), 120.0f);
                float w = exp2f(a);
                lsum[r] += w;
                msw[il][nt * 16 + l16] = (bf16_t)w;
            }
        }

#pragma unroll
        for (int kc = 0; kc < 2; kc++) {
            bf16x8 aw = *(const bf16x8*)&msw[wave * 16 + l16][kc * 32 + quad * 8];
#pragma unroll
            for (int dt = 0; dt < 4; dt++) {
                bf16x8 bv8 = *(const bf16x8*)&vT_s[dt * 16 + l16][kc * 32 + quad * 8];
                accO[dt] = __builtin_amdgcn_mfma_f32_16x16x32_bf16(aw, bv8, accO[dt], 0, 0, 0);
            }
        }
        __syncthreads();
    }

#pragma unroll
    for (int r = 0; r < 4; r++) {
#pragma unroll
        for (int off = 1; off < 16; off <<= 1) lsum[r] += __shfl_xor(lsum[r], off, 64);
    }

#pragma unroll
    for (int r = 0; r < 4; r++) {
        int il = wave * 16 + quad * 4 + r;
        int ig = i0 + il;
        float inv = 1.0f / lsum[r];
#pragma unroll
        for (int dt = 0; dt < 4; dt++) {
            CTX[((size_t)(b * Tt + ig)) * Cc + h * Dd + dt * 16 + l16] = accO[dt][r] * inv;
        }
    }
}

// ---------------------------------------------------------------------------
extern "C" void kernel_launch(void* const* d_in, const int* in_sizes, int n_in,
                              void* d_out, int out_size, void* d_ws, size_t ws_size,
                              hipStream_t stream)
{
    const float* query = (const float*)d_in[0];
    const float* key   = (const float*)d_in[1];
    const float* value = (const float*)d_in[2];
    const float* pemb  = (const float*)d_in[3];
    const float* Wq    = (const float*)d_in[4];
    const float* bq    = (const float*)d_in[5];
    const float* Wk    = (const float*)d_in[6];
    const float* bk    = (const float*)d_in[7];
    const float* Wv    = (const float*)d_in[8];
    const float* bv    = (const float*)d_in[9];
    const float* Wpos  = (const float*)d_in[10];
    const float* pbu   = (const float*)d_in[11];
    const float* pbv   = (const float*)d_in[12];
    const float* Wo    = (const float*)d_in[13];
    const float* bo    = (const float*)d_in[14];

    const size_t NE = (size_t)Bb * Hh * Tt * Dd;  // 4,194,304 per tensor
    bf16_t* QU  = (bf16_t*)d_ws;
    bf16_t* QV  = QU + NE;
    bf16_t* K16 = QV + NE;
    bf16_t* V16 = K16 + NE;
    bf16_t* P16 = V16 + NE;
    float*  CTX = (float*)(P16 + NE);             // ws >= 56 MB

    // QKVP projections (z = blockIdx.z)
    split_gemm_kernel<<<dim3(256, 1, 4), 256, 0, stream>>>(
        query, key, value, pemb, CTX, Wq, Wk, Wv, Wpos, Wo,
        bq, bk, bv, bo, pbu, pbv, QU, QV, K16, V16, P16, (float*)d_out, -1);

    attn_kernel<<<dim3(32, 32), 256, 0, stream>>>(QU, QV, K16, V16, P16, CTX);

    // output projection (mode 4)
    split_gemm_kernel<<<dim3(256, 1, 1), 256, 0, stream>>>(
        query, key, value, pemb, CTX, Wq, Wk, Wv, Wpos, Wo,
        bq, bk, bv, bo, pbu, pbv, QU, QV, K16, V16, P16, (float*)d_out, 4);
}

// Round 6
// 591.209 us; speedup vs baseline: 1.7527x; 1.0841x over previous
//
#include <hip/hip_runtime.h>

// ---------------------------------------------------------------------------
// RelPositionMultiHeadedAttention (Conformer / Transformer-XL rel-shift)
// B=4, T=2048, C=512, H=8, D=64
//
// R6 changes (attn only; split_gemm unchanged from R5):
//  - msw strip-local (79-col window per wave) [64][88]: LDS 54272->48128 B
//    => 3 blocks/CU even with 2KB LDS granule (49152*3 = 147456 <= 163840).
//  - grid axes swapped: blockIdx.x = bh -> all i-blocks of a head on one XCD
//    (K/V/P L2-resident: 4 bh x 768KB = 3MB < 4MB per-XCD L2).
//  - gather loop: weights buffered in regs, stored after all gathers (breaks
//    compiler-enforced LDS load/store alias serialization).
// ---------------------------------------------------------------------------

#define Bb 4
#define Tt 2048
#define Cc 512
#define Hh 8
#define Dd 64

typedef __bf16 bf16_t;
typedef __bf16 bf16x8 __attribute__((ext_vector_type(8)));
typedef float  f32x4  __attribute__((ext_vector_type(4)));

// ---------------------------------------------------------------------------
// Split-bf16 MFMA GEMM: Y = X @ W (+bias). X [8192,512] fp32, W [512,512] fp32.
// mode (modeArg<0 ? blockIdx.z : modeArg): 0=Q(->QU,QV) 1=K 2=V 3=P 4=out.
// ---------------------------------------------------------------------------
__global__ __launch_bounds__(256, 2)
void split_gemm_kernel(const float* __restrict__ Xq, const float* __restrict__ Xk,
                       const float* __restrict__ Xv, const float* __restrict__ Xp,
                       const float* __restrict__ Xc,
                       const float* __restrict__ Wq, const float* __restrict__ Wk,
                       const float* __restrict__ Wv, const float* __restrict__ Wp,
                       const float* __restrict__ Wo,
                       const float* __restrict__ bq, const float* __restrict__ bk,
                       const float* __restrict__ bv, const float* __restrict__ bo,
                       const float* __restrict__ bias_u, const float* __restrict__ bias_v,
                       bf16_t* __restrict__ QU, bf16_t* __restrict__ QV,
                       bf16_t* __restrict__ K16, bf16_t* __restrict__ V16,
                       bf16_t* __restrict__ P16, float* __restrict__ OUT,
                       int modeArg)
{
    const int z = (modeArg < 0) ? blockIdx.z : modeArg;
    const float* X    = (z == 0) ? Xq : (z == 1) ? Xk : (z == 2) ? Xv : (z == 3) ? Xp : Xc;
    const float* W    = (z == 0) ? Wq : (z == 1) ? Wk : (z == 2) ? Wv : (z == 3) ? Wp : Wo;
    const float* bias = (z == 0) ? bq : (z == 1) ? bk : (z == 2) ? bv : (z == 3) ? nullptr : bo;

    const int bx = blockIdx.x;
    const int g  = bx >> 3, x8 = bx & 7;
    const int mtile = (g >> 2) * 8 + x8;   // 0..63
    const int ntile = g & 3;               // 0..3
    const int r0 = mtile * 128;
    const int c0 = ntile * 128;

    const int tid  = threadIdx.x;
    const int wave = tid >> 6;
    const int lane = tid & 63;
    const int quad = lane >> 4;
    const int l16  = lane & 15;
    const int rb = (wave >> 1) * 64;
    const int cb = (wave & 1) * 64;

    __shared__ __align__(16) float Xs[128][68];
    __shared__ float Wt[128][65];

    f32x4 acc[4][4];
#pragma unroll
    for (int mt = 0; mt < 4; mt++)
#pragma unroll
        for (int nt = 0; nt < 4; nt++)
#pragma unroll
            for (int r = 0; r < 4; r++) acc[mt][nt][r] = 0.f;

    for (int it = 0; it < 8; ++it) {
        const int k0 = it * 64;
#pragma unroll
        for (int rep = 0; rep < 8; rep++) {
            int id = rep * 256 + tid;
            int m = id >> 4, c = id & 15;
            f32x4 v = *(const f32x4*)&X[(size_t)(r0 + m) * 512 + k0 + c * 4];
            *(f32x4*)&Xs[m][c * 4] = v;
        }
#pragma unroll
        for (int rep = 0; rep < 8; rep++) {
            int id = rep * 256 + tid;
            int cc = id & 31, kk = id >> 5;
            f32x4 v = *(const f32x4*)&W[(size_t)(k0 + kk) * 512 + c0 + cc * 4];
#pragma unroll
            for (int i = 0; i < 4; i++) Wt[cc * 4 + i][kk] = v[i];
        }
        __syncthreads();

#pragma unroll
        for (int kc = 0; kc < 2; kc++) {
            bf16x8 Bhi[4], Blo[4];
#pragma unroll
            for (int nt = 0; nt < 4; nt++) {
#pragma unroll
                for (int e = 0; e < 8; e++) {
                    float f = Wt[cb + nt * 16 + l16][kc * 32 + quad * 8 + e];
                    bf16_t hi = (bf16_t)f;
                    Bhi[nt][e] = hi;
                    Blo[nt][e] = (bf16_t)(f - (float)hi);
                }
            }
#pragma unroll
            for (int mt = 0; mt < 4; mt++) {
                f32x4 a0 = *(const f32x4*)&Xs[rb + mt * 16 + l16][kc * 32 + quad * 8];
                f32x4 a1 = *(const f32x4*)&Xs[rb + mt * 16 + l16][kc * 32 + quad * 8 + 4];
                bf16x8 Ahi, Alo;
#pragma unroll
                for (int e = 0; e < 4; e++) {
                    bf16_t h0 = (bf16_t)a0[e];
                    Ahi[e] = h0; Alo[e] = (bf16_t)(a0[e] - (float)h0);
                    bf16_t h1 = (bf16_t)a1[e];
                    Ahi[4 + e] = h1; Alo[4 + e] = (bf16_t)(a1[e] - (float)h1);
                }
#pragma unroll
                for (int nt = 0; nt < 4; nt++) {
                    acc[mt][nt] = __builtin_amdgcn_mfma_f32_16x16x32_bf16(Ahi, Bhi[nt], acc[mt][nt], 0, 0, 0);
                    acc[mt][nt] = __builtin_amdgcn_mfma_f32_16x16x32_bf16(Ahi, Blo[nt], acc[mt][nt], 0, 0, 0);
                    acc[mt][nt] = __builtin_amdgcn_mfma_f32_16x16x32_bf16(Alo, Bhi[nt], acc[mt][nt], 0, 0, 0);
                }
            }
        }
        __syncthreads();
    }

#pragma unroll
    for (int mt = 0; mt < 4; mt++) {
#pragma unroll
        for (int r = 0; r < 4; r++) {
            int row = r0 + rb + mt * 16 + quad * 4 + r;
#pragma unroll
            for (int nt = 0; nt < 4; nt++) {
                int col = c0 + cb + nt * 16 + l16;
                float y = acc[mt][nt][r] + (bias ? bias[col] : 0.f);
                if (z == 4) {
                    OUT[(size_t)row * 512 + col] = y;
                } else {
                    int b = row >> 11, t = row & 2047;
                    int h = col >> 6,  d = col & 63;
                    size_t idx = (((size_t)(b * Hh + h)) * Tt + t) * Dd + d;
                    if (z == 0) {
                        QU[idx] = (bf16_t)(y + bias_u[col]);
                        QV[idx] = (bf16_t)(y + bias_v[col]);
                    } else if (z == 1) {
                        K16[idx] = (bf16_t)y;
                    } else if (z == 2) {
                        V16[idx] = (bf16_t)y;
                    } else {
                        P16[idx] = (bf16_t)y;
                    }
                }
            }
        }
    }
}

// ---------------------------------------------------------------------------
// Kernel 2: attention. grid = (bh=32, itile=32) so same-bh blocks share XCD.
// LDS map (bytes), total 48128:
//   [0,     18432)  pA   [128][72] bf16: preamble qu rows 0..63 / qv rows
//                   64..128 (row 128 spills into k_s start, pre-loop only);
//                   then p band rows 0..(w1+w2)
//   [18432, 27648)  k_s  [64][72]
//   [27648, 36864)  vT_s [64][72]  ([d][j])
//   [36864, 48128)  msw  [64][88] bf16, wave-private strips, STRIP-LOCAL cols:
//                   col' = col_abs - 48 + wave*16; gather window [0,78];
//                   softmax weights later clobber cols 0..63 (after gathers).
// ---------------------------------------------------------------------------
__global__ __launch_bounds__(256, 3)
void attn_kernel(const bf16_t* __restrict__ QU, const bf16_t* __restrict__ QV,
                 const bf16_t* __restrict__ K16, const bf16_t* __restrict__ V16,
                 const bf16_t* __restrict__ P16, float* __restrict__ CTX)
{
    const int bh = blockIdx.x;                 // XCD locality: linear%8 = bh%8
    const int i0 = blockIdx.y * 64;
    const int b = bh >> 3, h = bh & 7;
    const int tid = threadIdx.x;
    const int wave = tid >> 6;
    const int lane = tid & 63;
    const int quad = lane >> 4;
    const int l16 = lane & 15;

    const size_t hb = (size_t)bh * Tt * Dd;
    const bf16_t* qu_g = QU + hb;
    const bf16_t* qv_g = QV + hb;
    const bf16_t* k_g  = K16 + hb;
    const bf16_t* v_g  = V16 + hb;
    const bf16_t* p_g  = P16 + hb;

    __shared__ __align__(16) char smem[48128];
    bf16_t (*pA)[72]   = (bf16_t (*)[72])(smem);           // 128 rows
    bf16_t (*k_s)[72]  = (bf16_t (*)[72])(smem + 18432);   // 64 rows
    bf16_t (*vT_s)[72] = (bf16_t (*)[72])(smem + 27648);   // 64 rows [d][j]
    bf16_t (*msw)[88]  = (bf16_t (*)[88])(smem + 36864);   // 64 rows, strip-local

    const int off_w = 48 - wave * 16;          // strip-local = absolute - off_w

    for (int idx = tid; idx < 64 * 8; idx += 256) {
        int row = idx >> 3, seg = idx & 7;
        *(f32x4*)&pA[row][seg * 8] = *(const f32x4*)(qu_g + (size_t)(i0 + row) * Dd + seg * 8);
    }
    for (int idx = tid; idx < 65 * 8; idx += 256) {
        int row = idx >> 3, seg = idx & 7;
        int gr = i0 + row; if (gr > Tt - 1) gr = Tt - 1;  // clamped row never gathered
        *(f32x4*)&pA[64 + row][seg * 8] = *(const f32x4*)(qv_g + (size_t)gr * Dd + seg * 8);
    }
    __syncthreads();

    bf16x8 aq[2], av1[2], av2[2];
#pragma unroll
    for (int kc = 0; kc < 2; kc++) {
        aq[kc]  = *(const bf16x8*)&pA[wave * 16 + l16][kc * 32 + quad * 8];
        av1[kc] = *(const bf16x8*)&pA[64 + wave * 16 + l16][kc * 32 + quad * 8];
        av2[kc] = *(const bf16x8*)&pA[64 + wave * 16 + l16 + 1][kc * 32 + quad * 8];
    }
    __syncthreads();  // q region about to be reused for p band

    float lsum[4];
    f32x4 accO[4];
#pragma unroll
    for (int r = 0; r < 4; r++) lsum[r] = 0.f;
#pragma unroll
    for (int dt = 0; dt < 4; dt++)
#pragma unroll
        for (int r = 0; r < 4; r++) accO[dt][r] = 0.f;

    const int cmin = 48 - wave * 16;   // absolute strip window
    const int cmax = 126 - wave * 16;

    for (int j0 = 0; j0 < Tt; j0 += 64) {
        int d_lo = i0 - (j0 + 63);
        int d_hi = i0 + 63 - j0;
        int w1 = 0, prow1 = 0;
        if (d_hi >= 0) {
            int b1 = d_lo > 0 ? d_lo : 0;
            w1 = d_hi - b1 + 1;
            prow1 = (Tt - 1) - d_hi;
        }
        int dmax2 = d_hi < -2 ? d_hi : -2;
        int w2 = 0, e_lo = 0;
        if (d_lo <= dmax2) {
            e_lo = -dmax2 - 2;
            int e_hi = -d_lo - 2;
            w2 = e_hi - e_lo + 1;
        }
        int c2_0 = d_hi + 2 + e_lo;
        int nct1 = (w1 + 15) >> 4;
        int nct2 = (w2 + 15) >> 4;

        for (int idx = tid; idx < 64 * 8; idx += 256) {
            int row = idx >> 3, seg = idx & 7;
            *(f32x4*)&k_s[row][seg * 8] = *(const f32x4*)(k_g + (size_t)(j0 + row) * Dd + seg * 8);
        }
        for (int idx = tid; idx < 64 * 8; idx += 256) {
            int j = idx & 63, seg = idx >> 6;
            bf16x8 tmp = *(const bf16x8*)(v_g + (size_t)(j0 + j) * Dd + seg * 8);
#pragma unroll
            for (int e = 0; e < 8; e++) vT_s[seg * 8 + e][j] = tmp[e];
        }
        for (int idx = tid; idx < (w1 + w2) * 8; idx += 256) {
            int rr = idx >> 3, seg = idx & 7;
            int srcrow = (rr < w1) ? (prow1 + rr) : (e_lo + rr - w1);
            *(f32x4*)&pA[rr][seg * 8] = *(const f32x4*)(p_g + (size_t)srcrow * Dd + seg * 8);
        }
        __syncthreads();

        f32x4 accS[4];
#pragma unroll
        for (int nt = 0; nt < 4; nt++) {
            f32x4 acc = {0.f, 0.f, 0.f, 0.f};
#pragma unroll
            for (int kc = 0; kc < 2; kc++) {
                bf16x8 bk8 = *(const bf16x8*)&k_s[nt * 16 + l16][kc * 32 + quad * 8];
                acc = __builtin_amdgcn_mfma_f32_16x16x32_bf16(aq[kc], bk8, acc, 0, 0, 0);
            }
            accS[nt] = acc;
        }

        // banded pos matmul -> strip-local skewed store (wave-private)
        for (int ct = 0; ct < nct1 + nct2; ct++) {
            bool b2 = ct >= nct1;
            int rb_ = b2 ? (w1 + (ct - nct1) * 16) : (ct * 16);
            int cb_ = b2 ? (c2_0 + (ct - nct1) * 16) : (ct * 16);
            if (cb_ > cmax || cb_ + 15 < cmin) continue;
            f32x4 acc = {0.f, 0.f, 0.f, 0.f};
#pragma unroll
            for (int kc = 0; kc < 2; kc++) {
                bf16x8 bp = *(const bf16x8*)&pA[rb_ + l16][kc * 32 + quad * 8];
                acc = b2 ? __builtin_amdgcn_mfma_f32_16x16x32_bf16(av2[kc], bp, acc, 0, 0, 0)
                         : __builtin_amdgcn_mfma_f32_16x16x32_bf16(av1[kc], bp, acc, 0, 0, 0);
            }
            int colp = cb_ + l16 - off_w;          // strip-local
            if ((unsigned)colp < 80u) {
#pragma unroll
                for (int r = 0; r < 4; r++)
                    msw[wave * 16 + quad * 4 + r][colp] = (bf16_t)acc[r];
            }
        }
        // zero column for dd == -1 (strip-local)
        {
            int zcl = d_hi + 1 - off_w;
            if ((unsigned)zcl < 80u && quad == 0)
                msw[wave * 16 + l16][zcl] = (bf16_t)0.f;
        }

        // gather all 16 (pipelined loads; no aliasing stores in between),
        // then write all 16 weights (strictly after all gathers)
        float wv[4][4];
#pragma unroll
        for (int nt = 0; nt < 4; nt++) {
#pragma unroll
            for (int r = 0; r < 4; r++) {
                // strip-local gather col = nt*16 + l16 + 15 - (quad*4 + r)
                float pos = (float)msw[wave * 16 + quad * 4 + r]
                                    [nt * 16 + l16 + 15 - (quad * 4 + r)];
                float x = accS[nt][r] + pos;
                float a = fminf(fmaf(x, 0.18033688f, -17.3123405f), 120.0f);
                float w = exp2f(a);
                lsum[r] += w;
                wv[nt][r] = w;
            }
        }
#pragma unroll
        for (int nt = 0; nt < 4; nt++)
#pragma unroll
            for (int r = 0; r < 4; r++)
                msw[wave * 16 + quad * 4 + r][nt * 16 + l16] = (bf16_t)wv[nt][r];

#pragma unroll
        for (int kc = 0; kc < 2; kc++) {
            bf16x8 aw = *(const bf16x8*)&msw[wave * 16 + l16][kc * 32 + quad * 8];
#pragma unroll
            for (int dt = 0; dt < 4; dt++) {
                bf16x8 bv8 = *(const bf16x8*)&vT_s[dt * 16 + l16][kc * 32 + quad * 8];
                accO[dt] = __builtin_amdgcn_mfma_f32_16x16x32_bf16(aw, bv8, accO[dt], 0, 0, 0);
            }
        }
        __syncthreads();
    }

#pragma unroll
    for (int r = 0; r < 4; r++) {
#pragma unroll
        for (int off = 1; off < 16; off <<= 1) lsum[r] += __shfl_xor(lsum[r], off, 64);
    }

#pragma unroll
    for (int r = 0; r < 4; r++) {
        int il = wave * 16 + quad * 4 + r;
        int ig = i0 + il;
        float inv = 1.0f / lsum[r];
#pragma unroll
        for (int dt = 0; dt < 4; dt++) {
            CTX[((size_t)(b * Tt + ig)) * Cc + h * Dd + dt * 16 + l16] = accO[dt][r] * inv;
        }
    }
}

// ---------------------------------------------------------------------------
extern "C" void kernel_launch(void* const* d_in, const int* in_sizes, int n_in,
                              void* d_out, int out_size, void* d_ws, size_t ws_size,
                              hipStream_t stream)
{
    const float* query = (const float*)d_in[0];
    const float* key   = (const float*)d_in[1];
    const float* value = (const float*)d_in[2];
    const float* pemb  = (const float*)d_in[3];
    const float* Wq    = (const float*)d_in[4];
    const float* bq    = (const float*)d_in[5];
    const float* Wk    = (const float*)d_in[6];
    const float* bk    = (const float*)d_in[7];
    const float* Wv    = (const float*)d_in[8];
    const float* bv    = (const float*)d_in[9];
    const float* Wpos  = (const float*)d_in[10];
    const float* pbu   = (const float*)d_in[11];
    const float* pbv   = (const float*)d_in[12];
    const float* Wo    = (const float*)d_in[13];
    const float* bo    = (const float*)d_in[14];

    const size_t NE = (size_t)Bb * Hh * Tt * Dd;  // 4,194,304 per tensor
    bf16_t* QU  = (bf16_t*)d_ws;
    bf16_t* QV  = QU + NE;
    bf16_t* K16 = QV + NE;
    bf16_t* V16 = K16 + NE;
    bf16_t* P16 = V16 + NE;
    float*  CTX = (float*)(P16 + NE);             // ws >= 56 MB

    // QKVP projections (z = blockIdx.z)
    split_gemm_kernel<<<dim3(256, 1, 4), 256, 0, stream>>>(
        query, key, value, pemb, CTX, Wq, Wk, Wv, Wpos, Wo,
        bq, bk, bv, bo, pbu, pbv, QU, QV, K16, V16, P16, (float*)d_out, -1);

    attn_kernel<<<dim3(32, 32), 256, 0, stream>>>(QU, QV, K16, V16, P16, CTX);

    // output projection (mode 4)
    split_gemm_kernel<<<dim3(256, 1, 1), 256, 0, stream>>>(
        query, key, value, pemb, CTX, Wq, Wk, Wv, Wpos, Wo,
        bq, bk, bv, bo, pbu, pbv, QU, QV, K16, V16, P16, (float*)d_out, 4);
}